// Round 2
// baseline (264.553 us; speedup 1.0000x reference)
//
#include <hip/hip_runtime.h>
#include <hip/hip_bf16.h>
#include <stdint.h>

#define NTEST 4096
#define NTRAIN 16384
#define DIM 128
#define KEXP 384   // [hi,hi,lo] x [hi,lo,hi] split-bf16 expansion
#define BK 96      // K-tile: 4 iterations, 48 MFMAs per barrier segment

typedef __attribute__((ext_vector_type(8))) short short8;
typedef __attribute__((ext_vector_type(4))) float float4v;

static __device__ __forceinline__ unsigned short f32_to_bf16_rne(float f) {
    union { float f; uint32_t u; } v; v.f = f;
    uint32_t u = v.u;
    uint32_t r = u + 0x7FFFu + ((u >> 16) & 1u);
    return (unsigned short)(r >> 16);
}
static __device__ __forceinline__ float bf16_bits_to_f32(unsigned short h) {
    union { uint32_t u; float f; } v; v.u = ((uint32_t)h) << 16;
    return v.f;
}

// ---- Kernel 1: per-column partial sums for std (coalesced) ----
__global__ void col_stats_partial(const float* __restrict__ train,
                                  float* __restrict__ psum, float* __restrict__ psumsq) {
    int b = blockIdx.x;       // 128 blocks x 128 rows each
    int t = threadIdx.x;      // 256
    int col = t & 127;
    int rh = t >> 7;          // 0/1
    float s = 0.f, ss = 0.f;
    int row0 = b * 128;
    for (int r = rh; r < 128; r += 2) {
        float x = train[(size_t)(row0 + r) * DIM + col];
        s += x; ss += x * x;
    }
    __shared__ float sh_s[256], sh_ss[256];
    sh_s[t] = s; sh_ss[t] = ss;
    __syncthreads();
    if (rh == 0) {
        psum[b * DIM + col]   = sh_s[col] + sh_s[col + 128];
        psumsq[b * DIM + col] = sh_ss[col] + sh_ss[col + 128];
    }
}

// ---- Kernel 2: bandwidth + Z scalars ----
__global__ void bandwidth_kernel(const float* __restrict__ psum, const float* __restrict__ psumsq,
                                 float* __restrict__ inv_bw, float* __restrict__ scalars) {
    int c = threadIdx.x; // 128
    float s = 0.f, ss = 0.f;
    for (int b = 0; b < 128; ++b) { s += psum[b * DIM + c]; ss += psumsq[b * DIM + c]; }
    float n = (float)NTRAIN;
    float var = (ss - s * s / n) / (n - 1.0f);
    float sd = fmaxf(sqrtf(var), 0.01f);
    float bw = 1.06f * sd * expf(-logf(n) / (float)(4 + DIM));
    bw = fminf(bw, 0.49f);
    inv_bw[c] = 1.0f / bw;
    __shared__ float sh[128];
    sh[c] = logf(bw);
    __syncthreads();
    for (int off = 64; off > 0; off >>= 1) {
        if (c < off) sh[c] += sh[c + off];
        __syncthreads();
    }
    if (c == 0) {
        float Z = 0.5f * (float)DIM * logf(2.0f * 3.14159265358979323846f) + sh[0] + logf(n);
        scalars[0] = -0.5f / Z;   // term = exp(scale*sq - 1)
    }
}

// ---- Kernel 3: scale by 1/bw, split bf16 hi/lo expansion, row norms, zero out ----
// 256 threads, 2 rows per block
__global__ void expand_kernel(const float* __restrict__ test, const float* __restrict__ train,
                              const float* __restrict__ inv_bw,
                              unsigned short* __restrict__ Ae, unsigned short* __restrict__ Be,
                              float* __restrict__ tnorm, float* __restrict__ rnorm,
                              float* __restrict__ out) {
    int t = threadIdx.x;
    int row = blockIdx.x * 2 + (t >> 7);   // 0..NTEST+NTRAIN-1
    int k = t & 127;
    bool is_test = row < NTEST;
    const float* src = is_test ? test : train;
    int r = is_test ? row : row - NTEST;
    float x = src[(size_t)r * DIM + k] * inv_bw[k];
    unsigned short hi = f32_to_bf16_rne(x);
    float lo_f = x - bf16_bits_to_f32(hi);
    unsigned short lo = f32_to_bf16_rne(lo_f);
    size_t base = (size_t)r * KEXP;
    if (is_test) {  // A' = [hi, hi, lo]
        Ae[base + k] = hi; Ae[base + DIM + k] = hi; Ae[base + 2 * DIM + k] = lo;
        if (k == 0) out[r] = 0.f;   // zero output (re-poisoned each call)
    } else {        // B' = [hi, lo, hi]  ->  A'.B' = hihi + hilo + lohi
        Be[base + k] = hi; Be[base + DIM + k] = lo; Be[base + 2 * DIM + k] = hi;
    }
    float nv = x * x;
    #pragma unroll
    for (int off = 32; off > 0; off >>= 1) nv += __shfl_xor(nv, off, 64);
    __shared__ float sh[4];
    if ((t & 63) == 0) sh[t >> 6] = nv;
    __syncthreads();
    if (k == 0) {
        float nrm = sh[(t >> 6)] + sh[(t >> 6) + 1];
        if (is_test) tnorm[r] = nrm; else rnorm[r] = nrm;
    }
}

// ---- Kernel 4: fused bf16 GEMM (K=384, BK=96) + exp epilogue + row-sum ----
__global__ __launch_bounds__(256) void kde_main(
    const unsigned short* __restrict__ Ae, const unsigned short* __restrict__ Be,
    const float* __restrict__ tnorm, const float* __restrict__ rnorm,
    const float* __restrict__ scalars, float* __restrict__ out) {

    __shared__ __align__(16) unsigned short As[128 * BK];  // 24 KB, rows of 96 bf16 (192 B)
    __shared__ __align__(16) unsigned short Bs[128 * BK];  // 24 KB

    const int t = threadIdx.x;
    const int m0 = blockIdx.y * 128;
    const int n0 = blockIdx.x * 128;
    const int wave = t >> 6;
    const int lane = t & 63;
    const int wm = wave >> 1, wn = wave & 1;
    const int lrow = lane & 15;        // A-row / B-col within 16-tile (operand layout)
    const int q = lane >> 4;           // k-quad

    float4v acc[4][4];
    #pragma unroll
    for (int i = 0; i < 4; ++i)
        #pragma unroll
        for (int j = 0; j < 4; ++j) {
            float4v z = {0.f, 0.f, 0.f, 0.f};
            acc[i][j] = z;
        }

    // precompute staging (row, kc) per chunk: 1536 16B chunks per tile, 12 per 192B row
    int srow[6], skc[6];
    #pragma unroll
    for (int rr = 0; rr < 6; ++rr) {
        int chunk = t + rr * 256;
        srow[rr] = chunk / 12;
        skc[rr] = chunk - srow[rr] * 12;   // 16B chunk within row
    }

    for (int kt = 0; kt < KEXP / BK; ++kt) {
        int k0 = kt * BK;
        #pragma unroll
        for (int rr = 0; rr < 6; ++rr) {
            int chunk = t + rr * 256;
            const unsigned short* ga = Ae + (size_t)(m0 + srow[rr]) * KEXP + k0 + skc[rr] * 8;
            __builtin_amdgcn_global_load_lds((const __attribute__((address_space(1))) void*)ga,
                (__attribute__((address_space(3))) void*)(As + chunk * 8), 16, 0, 0);
            const unsigned short* gb = Be + (size_t)(n0 + srow[rr]) * KEXP + k0 + skc[rr] * 8;
            __builtin_amdgcn_global_load_lds((const __attribute__((address_space(1))) void*)gb,
                (__attribute__((address_space(3))) void*)(Bs + chunk * 8), 16, 0, 0);
        }
        __syncthreads();

        #pragma unroll
        for (int kk = 0; kk < BK / 32; ++kk) {
            short8 af[4], bfr[4];
            #pragma unroll
            for (int tm = 0; tm < 4; ++tm)
                af[tm] = *(const short8*)(As + (wm * 64 + tm * 16 + lrow) * BK + kk * 32 + q * 8);
            #pragma unroll
            for (int tn = 0; tn < 4; ++tn)
                bfr[tn] = *(const short8*)(Bs + (wn * 64 + tn * 16 + lrow) * BK + kk * 32 + q * 8);
            #pragma unroll
            for (int tm = 0; tm < 4; ++tm)
                #pragma unroll
                for (int tn = 0; tn < 4; ++tn)
                    acc[tm][tn] = __builtin_amdgcn_mfma_f32_16x16x32_bf16(af[tm], bfr[tn], acc[tm][tn], 0, 0, 0);
        }
        __syncthreads();
    }

    const float scale = scalars[0];
    // Epilogue: C/D layout col=lane&15, row=q*4+reg
    #pragma unroll
    for (int tm = 0; tm < 4; ++tm) {
        #pragma unroll
        for (int r = 0; r < 4; ++r) {
            int grow = m0 + wm * 64 + tm * 16 + q * 4 + r;
            float tn_v = tnorm[grow];
            float rowsum = 0.f;
            #pragma unroll
            for (int tn = 0; tn < 4; ++tn) {
                int gcol = n0 + wn * 64 + tn * 16 + lrow;
                float d = acc[tm][tn][r];
                float sq = tn_v + rnorm[gcol] - 2.0f * d;
                sq = fmaxf(sq, 0.0f);
                rowsum += __expf(fmaf(scale, sq, -1.0f));
            }
            #pragma unroll
            for (int off = 1; off < 16; off <<= 1)
                rowsum += __shfl_xor(rowsum, off, 64);
            if (lrow == 0) atomicAdd(&out[grow], rowsum);
        }
    }
}

extern "C" void kernel_launch(void* const* d_in, const int* in_sizes, int n_in,
                              void* d_out, int out_size, void* d_ws, size_t ws_size,
                              hipStream_t stream) {
    const float* test  = (const float*)d_in[0];
    const float* train = (const float*)d_in[1];
    float* out = (float*)d_out;

    char* ws = (char*)d_ws;
    unsigned short* Ae = (unsigned short*)ws;                            // 4096*384*2  = 3,145,728 B
    unsigned short* Be = (unsigned short*)(ws + 3145728);                // 16384*384*2 = 12,582,912 B
    float* fws    = (float*)(ws + 3145728 + 12582912);
    float* tnorm  = fws;                 // 4096
    float* rnorm  = tnorm + NTEST;       // 16384
    float* psum   = rnorm + NTRAIN;      // 16384
    float* psumsq = psum + 16384;        // 16384
    float* inv_bw = psumsq + 16384;      // 128
    float* scalars = inv_bw + 128;       // 8

    hipLaunchKernelGGL(col_stats_partial, dim3(128), dim3(256), 0, stream, train, psum, psumsq);
    hipLaunchKernelGGL(bandwidth_kernel, dim3(1), dim3(128), 0, stream, psum, psumsq, inv_bw, scalars);
    hipLaunchKernelGGL(expand_kernel, dim3((NTEST + NTRAIN) / 2), dim3(256), 0, stream,
                       test, train, inv_bw, Ae, Be, tnorm, rnorm, out);
    hipLaunchKernelGGL(kde_main, dim3(NTRAIN / 128, NTEST / 128), dim3(256), 0, stream,
                       Ae, Be, tnorm, rnorm, scalars, out);
}

// Round 3
// 226.882 us; speedup vs baseline: 1.1660x; 1.1660x over previous
//
#include <hip/hip_runtime.h>
#include <hip/hip_bf16.h>
#include <stdint.h>

#define NTEST 4096
#define NTRAIN 16384
#define DIM 128
#define KEXP 256   // A'=[hi,hi] x B'=[hi,lo]  ->  dot = hi_t.(hi_r+lo_r) = hi_t.x_r
#define BK 32      // K-tile per barrier segment (R1-verified structure)

typedef __attribute__((ext_vector_type(8))) short short8;
typedef __attribute__((ext_vector_type(4))) float float4v;

static __device__ __forceinline__ unsigned short f32_to_bf16_rne(float f) {
    union { float f; uint32_t u; } v; v.f = f;
    uint32_t u = v.u;
    uint32_t r = u + 0x7FFFu + ((u >> 16) & 1u);
    return (unsigned short)(r >> 16);
}
static __device__ __forceinline__ float bf16_bits_to_f32(unsigned short h) {
    union { uint32_t u; float f; } v; v.u = ((uint32_t)h) << 16;
    return v.f;
}

// ---- Kernel 1: per-column partial sums for std (coalesced) ----
__global__ void col_stats_partial(const float* __restrict__ train,
                                  float* __restrict__ psum, float* __restrict__ psumsq) {
    int b = blockIdx.x;       // 128 blocks x 128 rows each
    int t = threadIdx.x;      // 256
    int col = t & 127;
    int rh = t >> 7;          // 0/1
    float s = 0.f, ss = 0.f;
    int row0 = b * 128;
    for (int r = rh; r < 128; r += 2) {
        float x = train[(size_t)(row0 + r) * DIM + col];
        s += x; ss += x * x;
    }
    __shared__ float sh_s[256], sh_ss[256];
    sh_s[t] = s; sh_ss[t] = ss;
    __syncthreads();
    if (rh == 0) {
        psum[b * DIM + col]   = sh_s[col] + sh_s[col + 128];
        psumsq[b * DIM + col] = sh_ss[col] + sh_ss[col + 128];
    }
}

// ---- Kernel 2: bandwidth + Z scalars ----
__global__ void bandwidth_kernel(const float* __restrict__ psum, const float* __restrict__ psumsq,
                                 float* __restrict__ inv_bw, float* __restrict__ scalars) {
    int c = threadIdx.x; // 128
    float s = 0.f, ss = 0.f;
    for (int b = 0; b < 128; ++b) { s += psum[b * DIM + c]; ss += psumsq[b * DIM + c]; }
    float n = (float)NTRAIN;
    float var = (ss - s * s / n) / (n - 1.0f);
    float sd = fmaxf(sqrtf(var), 0.01f);
    float bw = 1.06f * sd * expf(-logf(n) / (float)(4 + DIM));
    bw = fminf(bw, 0.49f);
    inv_bw[c] = 1.0f / bw;
    __shared__ float sh[128];
    sh[c] = logf(bw);
    __syncthreads();
    for (int off = 64; off > 0; off >>= 1) {
        if (c < off) sh[c] += sh[c + off];
        __syncthreads();
    }
    if (c == 0) {
        float Z = 0.5f * (float)DIM * logf(2.0f * 3.14159265358979323846f) + sh[0] + logf(n);
        scalars[0] = -0.5f / Z;   // term = exp(scale*sq - 1)
    }
}

// ---- Kernel 3: scale by 1/bw, split bf16 hi/lo expansion, row norms, zero out ----
// 256 threads, 2 rows per block
__global__ void expand_kernel(const float* __restrict__ test, const float* __restrict__ train,
                              const float* __restrict__ inv_bw,
                              unsigned short* __restrict__ Ae, unsigned short* __restrict__ Be,
                              float* __restrict__ tnorm, float* __restrict__ rnorm,
                              float* __restrict__ out) {
    int t = threadIdx.x;
    int row = blockIdx.x * 2 + (t >> 7);   // 0..NTEST+NTRAIN-1
    int k = t & 127;
    bool is_test = row < NTEST;
    const float* src = is_test ? test : train;
    int r = is_test ? row : row - NTEST;
    float x = src[(size_t)r * DIM + k] * inv_bw[k];
    unsigned short hi = f32_to_bf16_rne(x);
    size_t base = (size_t)r * KEXP;
    if (is_test) {  // A' = [hi, hi]
        Ae[base + k] = hi; Ae[base + DIM + k] = hi;
        if (k == 0) out[r] = 0.f;   // zero output (re-poisoned each call)
    } else {        // B' = [hi, lo]  ->  A'.B' = hi_t.hi_r + hi_t.lo_r = hi_t.x_r
        float lo_f = x - bf16_bits_to_f32(hi);
        unsigned short lo = f32_to_bf16_rne(lo_f);
        Be[base + k] = hi; Be[base + DIM + k] = lo;
    }
    float nv = x * x;   // norms use exact fp32 x (matches reference t*t)
    #pragma unroll
    for (int off = 32; off > 0; off >>= 1) nv += __shfl_xor(nv, off, 64);
    __shared__ float sh[4];
    if ((t & 63) == 0) sh[t >> 6] = nv;
    __syncthreads();
    if (k == 0) {
        float nrm = sh[(t >> 6)] + sh[(t >> 6) + 1];
        if (is_test) tnorm[r] = nrm; else rnorm[r] = nrm;
    }
}

// ---- Kernel 4: fused bf16 GEMM (K=256, BK=32) + exp epilogue + row-sum ----
__global__ __launch_bounds__(256) void kde_main(
    const unsigned short* __restrict__ Ae, const unsigned short* __restrict__ Be,
    const float* __restrict__ tnorm, const float* __restrict__ rnorm,
    const float* __restrict__ scalars, float* __restrict__ out) {

    __shared__ __align__(16) unsigned short As[128 * 32];  // 8 KB, rows of 32 bf16 (64 B)
    __shared__ __align__(16) unsigned short Bs[128 * 32];  // 8 KB

    const int t = threadIdx.x;
    const int m0 = blockIdx.y * 128;
    const int n0 = blockIdx.x * 128;
    const int wave = t >> 6;
    const int lane = t & 63;
    const int wm = wave >> 1, wn = wave & 1;
    const int lrow = lane & 15;        // A-row / B-col within 16-tile (operand layout)
    const int q = lane >> 4;           // k-quad

    float4v acc[4][4];
    #pragma unroll
    for (int i = 0; i < 4; ++i)
        #pragma unroll
        for (int j = 0; j < 4; ++j) {
            float4v z = {0.f, 0.f, 0.f, 0.f};
            acc[i][j] = z;
        }

    for (int kt = 0; kt < KEXP / 32; ++kt) {
        int k0 = kt * 32;
        // stage 8KB A-tile + 8KB B-tile: 512 chunks of 16B each, 256 threads x 2
        #pragma unroll
        for (int rr = 0; rr < 2; ++rr) {
            int chunk = t + rr * 256;         // 0..511
            int row = chunk >> 2;             // 4 x 16B per 64B row
            int kb = (chunk & 3) * 16;        // byte offset in row
            const unsigned short* ga = Ae + (size_t)(m0 + row) * KEXP + k0 + (kb >> 1);
            __builtin_amdgcn_global_load_lds((const __attribute__((address_space(1))) void*)ga,
                (__attribute__((address_space(3))) void*)(As + chunk * 8), 16, 0, 0);
            const unsigned short* gb = Be + (size_t)(n0 + row) * KEXP + k0 + (kb >> 1);
            __builtin_amdgcn_global_load_lds((const __attribute__((address_space(1))) void*)gb,
                (__attribute__((address_space(3))) void*)(Bs + chunk * 8), 16, 0, 0);
        }
        __syncthreads();

        short8 af[4], bfr[4];
        #pragma unroll
        for (int tm = 0; tm < 4; ++tm)
            af[tm] = *(const short8*)(As + (wm * 64 + tm * 16 + lrow) * 32 + q * 8);
        #pragma unroll
        for (int tn = 0; tn < 4; ++tn)
            bfr[tn] = *(const short8*)(Bs + (wn * 64 + tn * 16 + lrow) * 32 + q * 8);
        #pragma unroll
        for (int tm = 0; tm < 4; ++tm)
            #pragma unroll
            for (int tn = 0; tn < 4; ++tn)
                acc[tm][tn] = __builtin_amdgcn_mfma_f32_16x16x32_bf16(af[tm], bfr[tn], acc[tm][tn], 0, 0, 0);
        __syncthreads();
    }

    const float scale = scalars[0];
    // Epilogue: C/D layout col=lane&15, row=q*4+reg
    #pragma unroll
    for (int tm = 0; tm < 4; ++tm) {
        #pragma unroll
        for (int r = 0; r < 4; ++r) {
            int grow = m0 + wm * 64 + tm * 16 + q * 4 + r;
            float tn_v = tnorm[grow];
            float rowsum = 0.f;
            #pragma unroll
            for (int tn = 0; tn < 4; ++tn) {
                int gcol = n0 + wn * 64 + tn * 16 + lrow;
                float d = acc[tm][tn][r];
                float sq = tn_v + rnorm[gcol] - 2.0f * d;
                sq = fmaxf(sq, 0.0f);
                rowsum += __expf(fmaf(scale, sq, -1.0f));
            }
            #pragma unroll
            for (int off = 1; off < 16; off <<= 1)
                rowsum += __shfl_xor(rowsum, off, 64);
            if (lrow == 0) atomicAdd(&out[grow], rowsum);
        }
    }
}

extern "C" void kernel_launch(void* const* d_in, const int* in_sizes, int n_in,
                              void* d_out, int out_size, void* d_ws, size_t ws_size,
                              hipStream_t stream) {
    const float* test  = (const float*)d_in[0];
    const float* train = (const float*)d_in[1];
    float* out = (float*)d_out;

    char* ws = (char*)d_ws;
    unsigned short* Ae = (unsigned short*)ws;                            // 4096*256*2  = 2,097,152 B
    unsigned short* Be = (unsigned short*)(ws + 2097152);                // 16384*256*2 = 8,388,608 B
    float* fws    = (float*)(ws + 2097152 + 8388608);
    float* tnorm  = fws;                 // 4096
    float* rnorm  = tnorm + NTEST;       // 16384
    float* psum   = rnorm + NTRAIN;      // 16384
    float* psumsq = psum + 16384;        // 16384
    float* inv_bw = psumsq + 16384;      // 128
    float* scalars = inv_bw + 128;       // 8

    hipLaunchKernelGGL(col_stats_partial, dim3(128), dim3(256), 0, stream, train, psum, psumsq);
    hipLaunchKernelGGL(bandwidth_kernel, dim3(1), dim3(128), 0, stream, psum, psumsq, inv_bw, scalars);
    hipLaunchKernelGGL(expand_kernel, dim3((NTEST + NTRAIN) / 2), dim3(256), 0, stream,
                       test, train, inv_bw, Ae, Be, tnorm, rnorm, out);
    hipLaunchKernelGGL(kde_main, dim3(NTRAIN / 128, NTEST / 128), dim3(256), 0, stream,
                       Ae, Be, tnorm, rnorm, scalars, out);
}

// Round 4
// 152.851 us; speedup vs baseline: 1.7308x; 1.4843x over previous
//
#include <hip/hip_runtime.h>
#include <hip/hip_bf16.h>
#include <stdint.h>

#define NTEST 4096
#define NTRAIN 16384
#define DIM 128
#define KEXP 256   // A'=[hi,hi] x B'=[hi,lo]  ->  dot = hi_t.(hi_r+lo_r) = hi_t.x_r

typedef __attribute__((ext_vector_type(8))) short short8;
typedef __attribute__((ext_vector_type(4))) float float4v;

static __device__ __forceinline__ unsigned short f32_to_bf16_rne(float f) {
    union { float f; uint32_t u; } v; v.f = f;
    uint32_t u = v.u;
    uint32_t r = u + 0x7FFFu + ((u >> 16) & 1u);
    return (unsigned short)(r >> 16);
}
static __device__ __forceinline__ float bf16_bits_to_f32(unsigned short h) {
    union { uint32_t u; float f; } v; v.u = ((uint32_t)h) << 16;
    return v.f;
}

// ---- Kernel 1: per-column partial sums for std (coalesced) ----
__global__ void col_stats_partial(const float* __restrict__ train,
                                  float* __restrict__ psum, float* __restrict__ psumsq) {
    int b = blockIdx.x;       // 128 blocks x 128 rows each
    int t = threadIdx.x;      // 256
    int col = t & 127;
    int rh = t >> 7;          // 0/1
    float s = 0.f, ss = 0.f;
    int row0 = b * 128;
    for (int r = rh; r < 128; r += 2) {
        float x = train[(size_t)(row0 + r) * DIM + col];
        s += x; ss += x * x;
    }
    __shared__ float sh_s[256], sh_ss[256];
    sh_s[t] = s; sh_ss[t] = ss;
    __syncthreads();
    if (rh == 0) {
        psum[b * DIM + col]   = sh_s[col] + sh_s[col + 128];
        psumsq[b * DIM + col] = sh_ss[col] + sh_ss[col + 128];
    }
}

// ---- Kernel 2: bandwidth + Z scalars ----
__global__ void bandwidth_kernel(const float* __restrict__ psum, const float* __restrict__ psumsq,
                                 float* __restrict__ inv_bw, float* __restrict__ scalars) {
    int c = threadIdx.x; // 128
    float s = 0.f, ss = 0.f;
    for (int b = 0; b < 128; ++b) { s += psum[b * DIM + c]; ss += psumsq[b * DIM + c]; }
    float n = (float)NTRAIN;
    float var = (ss - s * s / n) / (n - 1.0f);
    float sd = fmaxf(sqrtf(var), 0.01f);
    float bw = 1.06f * sd * expf(-logf(n) / (float)(4 + DIM));
    bw = fminf(bw, 0.49f);
    inv_bw[c] = 1.0f / bw;
    __shared__ float sh[128];
    sh[c] = logf(bw);
    __syncthreads();
    for (int off = 64; off > 0; off >>= 1) {
        if (c < off) sh[c] += sh[c + off];
        __syncthreads();
    }
    if (c == 0) {
        float Z = 0.5f * (float)DIM * logf(2.0f * 3.14159265358979323846f) + sh[0] + logf(n);
        scalars[0] = -0.5f / Z;   // term = exp(scale*sq - 1)
    }
}

// ---- Kernel 3: scale by 1/bw, split bf16 hi/lo expansion, row norms, zero out ----
__global__ void expand_kernel(const float* __restrict__ test, const float* __restrict__ train,
                              const float* __restrict__ inv_bw,
                              unsigned short* __restrict__ Ae, unsigned short* __restrict__ Be,
                              float* __restrict__ tnorm, float* __restrict__ rnorm,
                              float* __restrict__ out) {
    int t = threadIdx.x;
    int row = blockIdx.x * 2 + (t >> 7);   // 0..NTEST+NTRAIN-1
    int k = t & 127;
    bool is_test = row < NTEST;
    const float* src = is_test ? test : train;
    int r = is_test ? row : row - NTEST;
    float x = src[(size_t)r * DIM + k] * inv_bw[k];
    unsigned short hi = f32_to_bf16_rne(x);
    size_t base = (size_t)r * KEXP;
    if (is_test) {  // A' = [hi, hi]
        Ae[base + k] = hi; Ae[base + DIM + k] = hi;
        if (k == 0) out[r] = 0.f;   // zero output (re-poisoned each call)
    } else {        // B' = [hi, lo]  ->  A'.B' = hi_t.hi_r + hi_t.lo_r = hi_t.x_r
        float lo_f = x - bf16_bits_to_f32(hi);
        unsigned short lo = f32_to_bf16_rne(lo_f);
        Be[base + k] = hi; Be[base + DIM + k] = lo;
    }
    float nv = x * x;   // norms use exact fp32 x (matches reference t*t)
    #pragma unroll
    for (int off = 32; off > 0; off >>= 1) nv += __shfl_xor(nv, off, 64);
    __shared__ float sh[4];
    if ((t & 63) == 0) sh[t >> 6] = nv;
    __syncthreads();
    if (k == 0) {
        float nrm = sh[(t >> 6)] + sh[(t >> 6) + 1];
        if (is_test) tnorm[r] = nrm; else rnorm[r] = nrm;
    }
}

// ---- Kernel 4: A-resident pipelined GEMM + exp epilogue ----
// Block: 64 test-rows (A in LDS over full K=256, XOR-swizzled), loops 8 n-tiles
// of 128 train-rows; B streamed in KC=64 chunks, double-buffered.
__global__ __launch_bounds__(256, 2) void kde_main(
    const unsigned short* __restrict__ Ae, const unsigned short* __restrict__ Be,
    const float* __restrict__ tnorm, const float* __restrict__ rnorm,
    const float* __restrict__ scalars, float* __restrict__ out) {

    __shared__ __align__(16) unsigned short As[64 * 256];   // 32 KB, swizzled chunks
    __shared__ __align__(16) unsigned short Bs[2 * 8192];   // 2 x 16 KB (KC=64: 2 kt-subtiles of 128x32)

    const int t = threadIdx.x;
    const int grp = blockIdx.x;          // 0..15 (n-group of 8 tiles)
    const int m0 = blockIdx.y * 64;      // 0..63 m-blocks
    const int wave = t >> 6;
    const int lane = t & 63;
    const int wm = wave >> 1, wn = wave & 1;
    const int lrow = lane & 15;
    const int q = lane >> 4;

    // ---- prologue: issue B segment 0 first (longest latency) ----
    {
        size_t nbase = ((size_t)(grp * 8 + 0) * 128) * 256 + 0 * 64;
        #pragma unroll
        for (int rr = 0; rr < 4; ++rr) {
            int c = t + rr * 256;            // 0..1023, 16B chunks
            int ktl = c >> 9;
            int row = (c >> 2) & 127;
            int kb = (c & 3) * 8;
            const unsigned short* gb = Be + nbase + (size_t)row * 256 + ktl * 32 + kb;
            __builtin_amdgcn_global_load_lds((const __attribute__((address_space(1))) void*)gb,
                (__attribute__((address_space(3))) void*)(Bs + c * 8), 16, 0, 0);
        }
    }
    // ---- stage A through registers with XOR chunk swizzle (bank-spread) ----
    #pragma unroll
    for (int rr = 0; rr < 8; ++rr) {
        int c = t + rr * 256;                // 0..2047: 64 rows x 32 chunks
        int row = c >> 5;
        int p = c & 31;
        float4 v = *(const float4*)(Ae + (size_t)(m0 + row) * 256 + p * 8);
        *(float4*)(As + row * 256 + ((p ^ (row & 7)) * 8)) = v;
    }
    // tnorm for this block's rows (once)
    float tnv[2][4];
    #pragma unroll
    for (int tm = 0; tm < 2; ++tm)
        #pragma unroll
        for (int r = 0; r < 4; ++r)
            tnv[tm][r] = tnorm[m0 + wm * 32 + tm * 16 + q * 4 + r];
    const float scale = scalars[0];

    int abase[2], arx[2];
    #pragma unroll
    for (int tm = 0; tm < 2; ++tm) {
        int row = wm * 32 + tm * 16 + lrow;
        abase[tm] = row * 256;
        arx[tm] = row & 7;
    }
    int boff[4];
    #pragma unroll
    for (int tn = 0; tn < 4; ++tn)
        boff[tn] = (wn * 64 + tn * 16 + lrow) * 32 + q * 8;

    __syncthreads();   // drains A ds_writes + B0 staging

    float4v acc[2][4];
    #pragma unroll
    for (int i = 0; i < 2; ++i)
        #pragma unroll
        for (int j = 0; j < 4; ++j) { float4v z = {0.f,0.f,0.f,0.f}; acc[i][j] = z; }
    float rs[2][4] = {{0.f,0.f,0.f,0.f},{0.f,0.f,0.f,0.f}};
    float rnv[4];

    // ---- 32 segments: 8 n-tiles x 4 K-chunks of 64 ----
    for (int s = 0; s < 32; ++s) {
        int buf = s & 1;
        if (s < 31) {   // prefetch next segment into other buffer
            int s2 = s + 1;
            int jj = s2 >> 2, kc = s2 & 3;
            size_t nbase = ((size_t)(grp * 8 + jj) * 128) * 256 + kc * 64;
            int obuf = buf ^ 1;
            #pragma unroll
            for (int rr = 0; rr < 4; ++rr) {
                int c = t + rr * 256;
                int ktl = c >> 9;
                int row = (c >> 2) & 127;
                int kb = (c & 3) * 8;
                const unsigned short* gb = Be + nbase + (size_t)row * 256 + ktl * 32 + kb;
                __builtin_amdgcn_global_load_lds((const __attribute__((address_space(1))) void*)gb,
                    (__attribute__((address_space(3))) void*)(Bs + obuf * 8192 + c * 8), 16, 0, 0);
            }
        }
        if ((s & 3) == 0) {   // prefetch rnorm for this n-tile (used 3 segments later)
            int n0j = (grp * 8 + (s >> 2)) * 128;
            #pragma unroll
            for (int tn = 0; tn < 4; ++tn)
                rnv[tn] = rnorm[n0j + wn * 64 + tn * 16 + lrow];
        }
        #pragma unroll
        for (int ktl = 0; ktl < 2; ++ktl) {
            int kt = (s & 3) * 2 + ktl;
            short8 af[2], bfv[4];
            #pragma unroll
            for (int tm = 0; tm < 2; ++tm)
                af[tm] = *(const short8*)(As + abase[tm] + ((((kt << 2) | q) ^ arx[tm]) << 3));
            #pragma unroll
            for (int tn = 0; tn < 4; ++tn)
                bfv[tn] = *(const short8*)(Bs + buf * 8192 + ktl * 4096 + boff[tn]);
            #pragma unroll
            for (int tm = 0; tm < 2; ++tm)
                #pragma unroll
                for (int tn = 0; tn < 4; ++tn)
                    acc[tm][tn] = __builtin_amdgcn_mfma_f32_16x16x32_bf16(af[tm], bfv[tn], acc[tm][tn], 0, 0, 0);
        }
        if ((s & 3) == 3) {   // n-tile complete: exp epilogue into register rowsums
            #pragma unroll
            for (int tm = 0; tm < 2; ++tm) {
                #pragma unroll
                for (int r = 0; r < 4; ++r) {
                    float c0 = tnv[tm][r];
                    float sum = 0.f;
                    #pragma unroll
                    for (int tn = 0; tn < 4; ++tn) {
                        float sq = fmaxf(c0 + rnv[tn] - 2.0f * acc[tm][tn][r], 0.0f);
                        sum += __expf(fmaf(scale, sq, -1.0f));
                    }
                    rs[tm][r] += sum;
                }
            }
            #pragma unroll
            for (int i = 0; i < 2; ++i)
                #pragma unroll
                for (int j = 0; j < 4; ++j) { float4v z = {0.f,0.f,0.f,0.f}; acc[i][j] = z; }
        }
        __syncthreads();
    }

    // ---- final: 16-lane reduce + one atomic per (tm,r) ----
    #pragma unroll
    for (int tm = 0; tm < 2; ++tm) {
        #pragma unroll
        for (int r = 0; r < 4; ++r) {
            float v = rs[tm][r];
            #pragma unroll
            for (int off = 1; off < 16; off <<= 1)
                v += __shfl_xor(v, off, 64);
            if (lrow == 0)
                atomicAdd(&out[m0 + wm * 32 + tm * 16 + q * 4 + r], v);
        }
    }
}

extern "C" void kernel_launch(void* const* d_in, const int* in_sizes, int n_in,
                              void* d_out, int out_size, void* d_ws, size_t ws_size,
                              hipStream_t stream) {
    const float* test  = (const float*)d_in[0];
    const float* train = (const float*)d_in[1];
    float* out = (float*)d_out;

    char* ws = (char*)d_ws;
    unsigned short* Ae = (unsigned short*)ws;                            // 4096*256*2  = 2,097,152 B
    unsigned short* Be = (unsigned short*)(ws + 2097152);                // 16384*256*2 = 8,388,608 B
    float* fws    = (float*)(ws + 2097152 + 8388608);
    float* tnorm  = fws;                 // 4096
    float* rnorm  = tnorm + NTEST;       // 16384
    float* psum   = rnorm + NTRAIN;      // 16384
    float* psumsq = psum + 16384;        // 16384
    float* inv_bw = psumsq + 16384;      // 128
    float* scalars = inv_bw + 128;       // 8

    hipLaunchKernelGGL(col_stats_partial, dim3(128), dim3(256), 0, stream, train, psum, psumsq);
    hipLaunchKernelGGL(bandwidth_kernel, dim3(1), dim3(128), 0, stream, psum, psumsq, inv_bw, scalars);
    hipLaunchKernelGGL(expand_kernel, dim3((NTEST + NTRAIN) / 2), dim3(256), 0, stream,
                       test, train, inv_bw, Ae, Be, tnorm, rnorm, out);
    hipLaunchKernelGGL(kde_main, dim3(16, 64), dim3(256), 0, stream,
                       Ae, Be, tnorm, rnorm, scalars, out);
}